// Round 3
// baseline (126.221 us; speedup 1.0000x reference)
//
#include <hip/hip_runtime.h>

typedef short v8s __attribute__((ext_vector_type(8)));
typedef float v4f __attribute__((ext_vector_type(4)));
typedef float v16f __attribute__((ext_vector_type(16)));

// RNE float -> bf16 (matches float_quantize(exp=8, man=7) for these inputs).
__device__ __forceinline__ unsigned short rne_bf16(float f) {
  unsigned u = __float_as_uint(f);
  return (unsigned short)((u + 0x7fffu + ((u >> 16) & 1u)) >> 16);
}
__device__ __forceinline__ float qbf(float f) {
  return __uint_as_float(((unsigned)rne_bf16(f)) << 16);
}

#define CS 72  // LDS col stride (shorts): 144 B; 16B-aligned, 4-way-benign

// ---------------------------------------------------------------------------
// wprep: 32 blocks. weights -> fragment-major Wt2:
//   Wt2[((pos*4 + kk)*4 + g)*512 + lane*8 + (c&7)],  g = n>>5 (0..3)
//   lane = (n&31) + 32*((c>>3)&1), kk = c>>4
// so conv's W loads are single fully-coalesced 1024-B v8s instructions.
// ---------------------------------------------------------------------------
__global__ __launch_bounds__(256) void wprep(const float* __restrict__ w,
                                             unsigned short* __restrict__ Wt2) {
  int t = blockIdx.x * 256 + threadIdx.x;  // 0..8191 = n*64 + c
  int n = t >> 6, c = t & 63;
  int kk = c >> 4;
  int lane = (n & 31) + 32 * ((c >> 3) & 1);
  const float* src = w + (size_t)t * 9;
#pragma unroll
  for (int pos = 0; pos < 9; ++pos) {
    int idx = (((pos * 4 + kk) * 4 + (n >> 5)) << 9) + lane * 8 + (c & 7);
    Wt2[idx] = rne_bf16(src[pos]);
  }
}

// ---------------------------------------------------------------------------
// conv (merged ch-halves): grid (14, 32) = 448 blocks, 256 thr = 4 waves.
// Each block computes ALL 128 out-channels for its 4-row tile:
//  - staging work halves vs the 2-half version (x staged once, not twice)
//  - 448 blocks @ 2 blocks/CU -> whole grid resident in ONE dispatch round
//    (no second-round convoy/tail)
// acc[4][2] v16f = 128 VGPR; W half-pos double-buffered wa/wb = 64 VGPR.
// Accumulation order per output chain identical to the verified kernel.
// Epilogue: 4 ct-quarters of the verified LDS-transpose + full-line stores;
// fbuf aliases xs (all compute precedes epilogue).
// ---------------------------------------------------------------------------
__global__ __launch_bounds__(256, 2) void conv(const float* __restrict__ x,
                                               const unsigned short* __restrict__ Wt2,
                                               const float* __restrict__ bias,
                                               float* __restrict__ out) {
  __shared__ __align__(16) char smem[6 * 58 * CS * 2 + 512];
  unsigned short* xs = (unsigned short*)smem;      // [6 rows][58 cols][64 c]
  float* fbuf = (float*)smem;                      // epilogue union: [32 ch][228]
  float* qb = (float*)(smem + 6 * 58 * CS * 2);    // 128 quantized biases

  const int quad = blockIdx.x, b = blockIdx.y;
  const int oh0 = quad * 4;
  const int tid = threadIdx.x;
  const int wv = tid >> 6, lane = tid & 63;
  const int lj = lane & 31, lh = lane >> 5;
  const int lj1 = 28 + (lj < 27 ? lj : 27);  // sp-tile1 col offset (clamped)

  if (tid < 128) qb[tid] = qbf(bias[tid]);

  // ---- fused staging: x fp32 -> RNE bf16 -> xs (transposed), borders zeroed
  // 672 quad-slots = 6 rows * 8 chan-octets * 14 w-quads; 4 w per thread-slot.
  const float* xb0 = x + (size_t)b * 64 * 3136;
#pragma unroll
  for (int it = 0; it < 3; ++it) {
    int i = it * 256 + tid;
    if (i < 672) {
      int c8 = i & 7, jj = i >> 3;        // c8 innermost: LDS-conflict-free
      int r = jj / 14, wq = jj - r * 14;  // r: 0..5, wq: 0..13
      int h_in = oh0 + r - 1;             // input row (pad rows -> zeros)
      unsigned short* dstp = &xs[(r * 58 + 1 + wq * 4) * CS + c8 * 8];
      if ((unsigned)h_in < 56u) {
        const float* xb = xb0 + (size_t)(c8 * 8) * 3136 + h_in * 56 + wq * 4;
        v4f f[8];
#pragma unroll
        for (int jc = 0; jc < 8; ++jc) f[jc] = *(const v4f*)&xb[(size_t)jc * 3136];
#pragma unroll
        for (int k = 0; k < 4; ++k) {
          v8s pk;
#pragma unroll
          for (int jc = 0; jc < 8; ++jc) pk[jc] = (short)rne_bf16(f[jc][k]);
          *(v8s*)&dstp[k * CS] = pk;
        }
      } else {
        v8s z;
#pragma unroll
        for (int e = 0; e < 8; ++e) z[e] = 0;
#pragma unroll
        for (int k = 0; k < 4; ++k) *(v8s*)&dstp[k * CS] = z;
      }
    }
  }
  // zero col borders (w = -1 and 56): 6 rows * 2 cols * 8 octets = 96 slots
  if (tid < 96) {
    int r = tid >> 4, q = tid & 15;
    int col = (q >> 3) ? 57 : 0;
    v8s z;
#pragma unroll
    for (int e = 0; e < 8; ++e) z[e] = 0;
    *(v8s*)&xs[(r * 58 + col) * CS + (q & 7) * 8] = z;
  }
  __syncthreads();

  // ---- W fragments: 4 n-groups per kk; half-pos double buffer (wa=kk01,
  // wb=kk23). Loads for (pos+1, half) issue right after (pos, half)'s MFMAs,
  // so L2 latency hides under the other half's 16 MFMAs.
  const unsigned short* wt0 = Wt2 + lane * 8;
  v8s wa[8], wb[8];
#define WLOADH(POS, HALF, BUF)                                               \
  {                                                                          \
    _Pragma("unroll") for (int kk2 = 0; kk2 < 2; ++kk2) {                    \
      _Pragma("unroll") for (int g = 0; g < 4; ++g) {                        \
        BUF[kk2 * 4 + g] =                                                   \
            *(const v8s*)(wt0 + ((((POS)*4 + (HALF)*2 + kk2) * 4 + g) << 9));\
      }                                                                      \
    }                                                                        \
  }

  v16f acc[4][2];  // [n-group][sp tile]
#pragma unroll
  for (int a = 0; a < 4; ++a)
#pragma unroll
    for (int s = 0; s < 2; ++s)
#pragma unroll
      for (int e = 0; e < 16; ++e) acc[a][s][e] = 0.0f;

#define COMPH(POS, HALF, BUF)                                                  \
  {                                                                            \
    const int kh = (POS) / 3, kw = (POS) % 3;                                  \
    const unsigned short* p0 = xs + ((wv + kh) * 58 + kw + lj) * CS + lh * 8;  \
    const unsigned short* p1 = xs + ((wv + kh) * 58 + kw + lj1) * CS + lh * 8; \
    _Pragma("unroll") for (int kk2 = 0; kk2 < 2; ++kk2) {                      \
      v8s f0 = *(const v8s*)(p0 + ((HALF)*2 + kk2) * 16);                      \
      v8s f1 = *(const v8s*)(p1 + ((HALF)*2 + kk2) * 16);                      \
      _Pragma("unroll") for (int g = 0; g < 4; ++g) {                          \
        acc[g][0] = __builtin_amdgcn_mfma_f32_32x32x16_bf16(BUF[kk2 * 4 + g], f0, acc[g][0], 0, 0, 0); \
        acc[g][1] = __builtin_amdgcn_mfma_f32_32x32x16_bf16(BUF[kk2 * 4 + g], f1, acc[g][1], 0, 0, 0); \
      }                                                                        \
    }                                                                          \
  }

  WLOADH(0, 0, wa); WLOADH(0, 1, wb);
  COMPH(0, 0, wa); WLOADH(1, 0, wa); COMPH(0, 1, wb); WLOADH(1, 1, wb);
  COMPH(1, 0, wa); WLOADH(2, 0, wa); COMPH(1, 1, wb); WLOADH(2, 1, wb);
  COMPH(2, 0, wa); WLOADH(3, 0, wa); COMPH(2, 1, wb); WLOADH(3, 1, wb);
  COMPH(3, 0, wa); WLOADH(4, 0, wa); COMPH(3, 1, wb); WLOADH(4, 1, wb);
  COMPH(4, 0, wa); WLOADH(5, 0, wa); COMPH(4, 1, wb); WLOADH(5, 1, wb);
  COMPH(5, 0, wa); WLOADH(6, 0, wa); COMPH(5, 1, wb); WLOADH(6, 1, wb);
  COMPH(6, 0, wa); WLOADH(7, 0, wa); COMPH(6, 1, wb); WLOADH(7, 1, wb);
  COMPH(7, 0, wa); WLOADH(8, 0, wa); COMPH(7, 1, wb); WLOADH(8, 1, wb);
  COMPH(8, 0, wa); COMPH(8, 1, wb);

  // ---- epilogue: 4 ct-quarters of LDS transpose -> full-line stores ----
  __syncthreads();  // all xs reads done; fbuf may now alias xs
#pragma unroll
  for (int q = 0; q < 4; ++q) {
    if (lj < 28) {
#pragma unroll
      for (int e = 0; e < 16; ++e) {
        int chl = (e & 3) + 8 * (e >> 2) + 4 * lh;  // 0..31 (C/D layout, verified)
        fbuf[chl * 228 + wv * 56 + lj] = acc[q][0][e];
        fbuf[chl * 228 + wv * 56 + 28 + lj] = acc[q][1][e];
      }
    }
    __syncthreads();
#pragma unroll
    for (int p = 0; p < 8; ++p) {
      int i = p * 256 + tid;
      int chl = i >> 6, j = i & 63;
      if (j < 56) {
        v4f v = *(const v4f*)&fbuf[chl * 228 + j * 4];
        float bb = qb[q * 32 + chl];
        v[0] += bb; v[1] += bb; v[2] += bb; v[3] += bb;
        float* dst = out + (size_t)(b * 128 + q * 32 + chl) * 3136 + quad * 224 + j * 4;
        *(v4f*)dst = v;
      }
    }
    if (q < 3) __syncthreads();  // readers done before next quarter overwrites
  }
}

extern "C" void kernel_launch(void* const* d_in, const int* in_sizes, int n_in,
                              void* d_out, int out_size, void* d_ws, size_t ws_size,
                              hipStream_t stream) {
  const float* x = (const float*)d_in[0];     // [32,64,56,56]
  const float* w = (const float*)d_in[1];     // [128,64,3,3]
  const float* bias = (const float*)d_in[2];  // [128]
  float* out = (float*)d_out;                 // [32,128,56,56] fp32

  unsigned short* Wt2 = (unsigned short*)d_ws;  // 147 KB

  wprep<<<32, 256, 0, stream>>>(w, Wt2);
  conv<<<dim3(14, 32), 256, 0, stream>>>(x, Wt2, bias, out);
}

// Round 4
// 115.072 us; speedup vs baseline: 1.0969x; 1.0969x over previous
//
#include <hip/hip_runtime.h>

typedef short v8s __attribute__((ext_vector_type(8)));
typedef float v4f __attribute__((ext_vector_type(4)));
typedef float v16f __attribute__((ext_vector_type(16)));

// RNE float -> bf16 (matches float_quantize(exp=8, man=7) for these inputs).
__device__ __forceinline__ unsigned short rne_bf16(float f) {
  unsigned u = __float_as_uint(f);
  return (unsigned short)((u + 0x7fffu + ((u >> 16) & 1u)) >> 16);
}
__device__ __forceinline__ float qbf(float f) {
  return __uint_as_float(((unsigned)rne_bf16(f)) << 16);
}

#define CS 72  // LDS col stride (shorts): 144 B; 16B-aligned, 4-way-benign

// ---------------------------------------------------------------------------
// wprep: 32 blocks. weights -> fragment-major Wt2:
//   Wt2[((pos*4 + kk)*4 + g)*512 + lane*8 + (c&7)],  g = n>>5 (0..3)
//   lane = (n&31) + 32*((c>>3)&1), kk = c>>4
// so conv's W loads are single fully-coalesced 1024-B v8s instructions.
// ---------------------------------------------------------------------------
__global__ __launch_bounds__(256) void wprep(const float* __restrict__ w,
                                             unsigned short* __restrict__ Wt2) {
  int t = blockIdx.x * 256 + threadIdx.x;  // 0..8191 = n*64 + c
  int n = t >> 6, c = t & 63;
  int kk = c >> 4;
  int lane = (n & 31) + 32 * ((c >> 3) & 1);
  const float* src = w + (size_t)t * 9;
#pragma unroll
  for (int pos = 0; pos < 9; ++pos) {
    int idx = (((pos * 4 + kk) * 4 + (n >> 5)) << 9) + lane * 8 + (c & 7);
    Wt2[idx] = rne_bf16(src[pos]);
  }
}

// ---------------------------------------------------------------------------
// conv: 2-row x 128-ch tiles. grid (28 row-pairs, 32 b) = 896 blocks, 4 waves.
// Round-3 post-mortem: 448 blocks = 1.75 blocks/CU = 16.5% occupancy ->
// latency-bound (MfmaUtil 11%). This version keeps x staged ONCE (merged
// 128-ch) but halves tile height: LDS 34 KB -> 4 blocks/CU, whole grid
// resident (~44% occupancy), co-resident blocks overlap phases.
// Wave wv: row rw = wv&1, ch-groups gg2 = (wv>>1)*2 .. +1 (64 ch), 56 w.
// acc[2][2]; W half-pos double-buffered (4+4 v8s). Accumulation order per
// output chain identical to the verified kernel (pos-major, kk-ordered).
// Epilogue: 2 row-passes, fbuf[128][60] transpose (stride 60: v4f-aligned),
// 7 v4f stores/thread. fbuf aliases xs (all compute precedes epilogue).
// ---------------------------------------------------------------------------
__global__ __launch_bounds__(256, 4) void conv(const float* __restrict__ x,
                                               const unsigned short* __restrict__ Wt2,
                                               const float* __restrict__ bias,
                                               float* __restrict__ out) {
  __shared__ __align__(16) char smem[4 * 58 * CS * 2 + 512];
  unsigned short* xs = (unsigned short*)smem;      // [4 rows][58 cols][64 c]
  float* fbuf = (float*)smem;                      // epilogue union: [128][60]
  float* qb = (float*)(smem + 4 * 58 * CS * 2);    // 128 quantized biases

  const int pair = blockIdx.x, b = blockIdx.y;
  const int oh0 = pair * 2;
  const int tid = threadIdx.x;
  const int wv = tid >> 6, lane = tid & 63;
  const int lj = lane & 31, lh = lane >> 5;
  const int lj1 = 28 + (lj < 27 ? lj : 27);  // sp-tile1 col offset (clamped)
  const int rw = wv & 1;                     // wave's output row within pair
  const int gg2 = (wv >> 1) * 2;             // wave's first 32-ch group

  if (tid < 128) qb[tid] = qbf(bias[tid]);

  // ---- fused staging: x fp32 -> RNE bf16 -> xs (transposed), borders zeroed
  // 448 slots = 4 rows * 8 chan-octets * 14 w-quads; 4 w per thread-slot.
  const float* xb0 = x + (size_t)b * 64 * 3136;
#pragma unroll
  for (int it = 0; it < 2; ++it) {
    int i = it * 256 + tid;
    if (i < 448) {
      int c8 = i & 7, jj = i >> 3;        // c8 innermost: LDS-conflict-free
      int r = jj / 14, wq = jj - r * 14;  // r: 0..3, wq: 0..13
      int h_in = oh0 + r - 1;             // input row (pad rows -> zeros)
      unsigned short* dstp = &xs[(r * 58 + 1 + wq * 4) * CS + c8 * 8];
      if ((unsigned)h_in < 56u) {
        const float* xb = xb0 + (size_t)(c8 * 8) * 3136 + h_in * 56 + wq * 4;
        v4f f[8];
#pragma unroll
        for (int jc = 0; jc < 8; ++jc) f[jc] = *(const v4f*)&xb[(size_t)jc * 3136];
#pragma unroll
        for (int k = 0; k < 4; ++k) {
          v8s pk;
#pragma unroll
          for (int jc = 0; jc < 8; ++jc) pk[jc] = (short)rne_bf16(f[jc][k]);
          *(v8s*)&dstp[k * CS] = pk;
        }
      } else {
        v8s z;
#pragma unroll
        for (int e = 0; e < 8; ++e) z[e] = 0;
#pragma unroll
        for (int k = 0; k < 4; ++k) *(v8s*)&dstp[k * CS] = z;
      }
    }
  }
  // zero col borders (w = -1 and 56): 4 rows * 2 cols * 8 octets = 64 slots
  if (tid < 64) {
    int r = tid >> 4, q = tid & 15;
    int col = (q >> 3) ? 57 : 0;
    v8s z;
#pragma unroll
    for (int e = 0; e < 8; ++e) z[e] = 0;
    *(v8s*)&xs[(r * 58 + col) * CS + (q & 7) * 8] = z;
  }

  // ---- W fragments for this wave's 2 ch-groups; half-pos double buffer.
  // Issued before the barrier so L2 latency overlaps the barrier wait.
  const unsigned short* wt0 = Wt2 + lane * 8;
  v8s wa[4], wb[4];
#define WLOADH(POS, HALF, BUF)                                                 \
  {                                                                            \
    _Pragma("unroll") for (int kk2 = 0; kk2 < 2; ++kk2) {                      \
      _Pragma("unroll") for (int gi = 0; gi < 2; ++gi) {                       \
        BUF[kk2 * 2 + gi] = *(const v8s*)(                                     \
            wt0 + ((((POS)*4 + (HALF)*2 + kk2) * 4 + gg2 + gi) << 9));         \
      }                                                                        \
    }                                                                          \
  }
  WLOADH(0, 0, wa);
  WLOADH(0, 1, wb);
  __syncthreads();

  v16f acc[2][2];  // [n-group][sp tile]
#pragma unroll
  for (int a = 0; a < 2; ++a)
#pragma unroll
    for (int s = 0; s < 2; ++s)
#pragma unroll
      for (int e = 0; e < 16; ++e) acc[a][s][e] = 0.0f;

#define COMPH(POS, HALF, BUF)                                                  \
  {                                                                            \
    const int kh = (POS) / 3, kw = (POS) % 3;                                  \
    const unsigned short* p0 = xs + ((rw + kh) * 58 + kw + lj) * CS + lh * 8;  \
    const unsigned short* p1 = xs + ((rw + kh) * 58 + kw + lj1) * CS + lh * 8; \
    _Pragma("unroll") for (int kk2 = 0; kk2 < 2; ++kk2) {                      \
      v8s f0 = *(const v8s*)(p0 + ((HALF)*2 + kk2) * 16);                      \
      v8s f1 = *(const v8s*)(p1 + ((HALF)*2 + kk2) * 16);                      \
      _Pragma("unroll") for (int gi = 0; gi < 2; ++gi) {                       \
        acc[gi][0] = __builtin_amdgcn_mfma_f32_32x32x16_bf16(BUF[kk2 * 2 + gi], f0, acc[gi][0], 0, 0, 0); \
        acc[gi][1] = __builtin_amdgcn_mfma_f32_32x32x16_bf16(BUF[kk2 * 2 + gi], f1, acc[gi][1], 0, 0, 0); \
      }                                                                        \
    }                                                                          \
  }

  COMPH(0, 0, wa); WLOADH(1, 0, wa); COMPH(0, 1, wb); WLOADH(1, 1, wb);
  COMPH(1, 0, wa); WLOADH(2, 0, wa); COMPH(1, 1, wb); WLOADH(2, 1, wb);
  COMPH(2, 0, wa); WLOADH(3, 0, wa); COMPH(2, 1, wb); WLOADH(3, 1, wb);
  COMPH(3, 0, wa); WLOADH(4, 0, wa); COMPH(3, 1, wb); WLOADH(4, 1, wb);
  COMPH(4, 0, wa); WLOADH(5, 0, wa); COMPH(4, 1, wb); WLOADH(5, 1, wb);
  COMPH(5, 0, wa); WLOADH(6, 0, wa); COMPH(5, 1, wb); WLOADH(6, 1, wb);
  COMPH(6, 0, wa); WLOADH(7, 0, wa); COMPH(6, 1, wb); WLOADH(7, 1, wb);
  COMPH(7, 0, wa); WLOADH(8, 0, wa); COMPH(7, 1, wb); WLOADH(8, 1, wb);
  COMPH(8, 0, wa); COMPH(8, 1, wb);

  // ---- epilogue: 2 row-passes of LDS transpose -> v4f stores ----
  __syncthreads();  // all xs reads done; fbuf may now alias xs
#pragma unroll
  for (int p = 0; p < 2; ++p) {
    if ((wv & 1) == p && lj < 28) {
#pragma unroll
      for (int gi = 0; gi < 2; ++gi) {
#pragma unroll
        for (int e = 0; e < 16; ++e) {
          int chl = (e & 3) + 8 * (e >> 2) + 4 * lh;  // 0..31 (C/D layout, verified)
          int ch = (gg2 + gi) * 32 + chl;
          fbuf[ch * 60 + lj] = acc[gi][0][e];
          fbuf[ch * 60 + 28 + lj] = acc[gi][1][e];
        }
      }
    }
    __syncthreads();
    {
      int ch = tid >> 1, hf = tid & 1;
      float bb = qb[ch];
      const float* src = &fbuf[ch * 60 + hf * 28];
      float* dst = out + (size_t)(b * 128 + ch) * 3136 + (oh0 + p) * 56 + hf * 28;
#pragma unroll
      for (int k = 0; k < 7; ++k) {
        v4f v = *(const v4f*)&src[k * 4];
        v[0] += bb; v[1] += bb; v[2] += bb; v[3] += bb;
        *(v4f*)&dst[k * 4] = v;
      }
    }
    if (p == 0) __syncthreads();  // readers done before pass-1 overwrites fbuf
  }
}

extern "C" void kernel_launch(void* const* d_in, const int* in_sizes, int n_in,
                              void* d_out, int out_size, void* d_ws, size_t ws_size,
                              hipStream_t stream) {
  const float* x = (const float*)d_in[0];     // [32,64,56,56]
  const float* w = (const float*)d_in[1];     // [128,64,3,3]
  const float* bias = (const float*)d_in[2];  // [128]
  float* out = (float*)d_out;                 // [32,128,56,56] fp32

  unsigned short* Wt2 = (unsigned short*)d_ws;  // 147 KB

  wprep<<<32, 256, 0, stream>>>(w, Wt2);
  conv<<<dim3(28, 32), 256, 0, stream>>>(x, Wt2, bias, out);
}

// Round 5
// 114.462 us; speedup vs baseline: 1.1027x; 1.0053x over previous
//
#include <hip/hip_runtime.h>

typedef short v8s __attribute__((ext_vector_type(8)));
typedef float v4f __attribute__((ext_vector_type(4)));
typedef float v16f __attribute__((ext_vector_type(16)));

// RNE float -> bf16 (matches float_quantize(exp=8, man=7) for these inputs).
__device__ __forceinline__ unsigned short rne_bf16(float f) {
  unsigned u = __float_as_uint(f);
  return (unsigned short)((u + 0x7fffu + ((u >> 16) & 1u)) >> 16);
}
__device__ __forceinline__ float qbf(float f) {
  return __uint_as_float(((unsigned)rne_bf16(f)) << 16);
}

#define CS 72  // LDS col stride (shorts): 144 B; 16B-aligned, conflict-benign

// ---------------------------------------------------------------------------
// wprep: 32 blocks. weights -> fragment-major Wt2:
//   Wt2[((pos*4 + kk)*4 + g)*512 + lane*8 + (c&7)],  g = n>>5 (0..3)
//   lane = (n&31) + 32*((c>>3)&1), kk = c>>4
// ---------------------------------------------------------------------------
__global__ __launch_bounds__(256) void wprep(const float* __restrict__ w,
                                             unsigned short* __restrict__ Wt2) {
  int t = blockIdx.x * 256 + threadIdx.x;  // 0..8191 = n*64 + c
  int n = t >> 6, c = t & 63;
  int kk = c >> 4;
  int lane = (n & 31) + 32 * ((c >> 3) & 1);
  const float* src = w + (size_t)t * 9;
#pragma unroll
  for (int pos = 0; pos < 9; ++pos) {
    int idx = (((pos * 4 + kk) * 4 + (n >> 5)) << 9) + lane * 8 + (c & 7);
    Wt2[idx] = rne_bf16(src[pos]);
  }
}

// ---------------------------------------------------------------------------
// conv, 2-tile software pipeline (round-4 post-mortem: phase convoy -> >50%
// stall; MfmaUtil 14 / VALU 7 / HBM 24, all idle). Grid (28 pairs, 16 b2);
// block does b = 2*b2 (tile0) and 2*b2+1 (tile1) for its 2-row x 128-ch tile.
//   stage(t0) -> [compute(t0) WHILE t1's 16 global_load_dwordx4 in flight
//   into pf regs] -> epilogue(t0) -> quant+ds_write(t1) [loads long done]
//   -> compute(t1) -> epilogue(t1).
// t1's HBM fetch hides under t0's 144 MFMAs + stores (T14 issue-early/
// write-late). Single xs buffer: t1 write happens after epilogue(t0) frees it.
// VGPR: acc 64 + pf 64 + wa/wb 32 + misc -> ~190, 2 waves/SIMD, 2 blocks/CU.
// Accumulation order per output chain identical to the verified kernel.
// ---------------------------------------------------------------------------
__global__ __launch_bounds__(256, 2) void conv(const float* __restrict__ x,
                                               const unsigned short* __restrict__ Wt2,
                                               const float* __restrict__ bias,
                                               float* __restrict__ out) {
  __shared__ __align__(16) char smem[4 * 58 * CS * 2 + 512];
  unsigned short* xs = (unsigned short*)smem;      // [4 rows][58 cols][64 c]
  float* fbuf = (float*)smem;                      // epilogue union: [128][60]
  float* qb = (float*)(smem + 4 * 58 * CS * 2);    // 128 quantized biases

  const int pair = blockIdx.x, b2 = blockIdx.y;
  const int oh0 = pair * 2;
  const int tid = threadIdx.x;
  const int wv = tid >> 6, lane = tid & 63;
  const int lj = lane & 31, lh = lane >> 5;
  const int lj1 = 28 + (lj < 27 ? lj : 27);  // sp-tile1 col offset (clamped)
  const int rw = wv & 1;                     // wave's output row within pair
  const int gg2 = (wv >> 1) * 2;             // wave's first 32-ch group

  if (tid < 128) qb[tid] = qbf(bias[tid]);

  // slot decode, shared by both tiles (448 slots = 4r * 8c8 * 14wq):
  // slot0: i = tid (always valid); slot1: i = 256+tid (valid if tid<192).
  const int c8 = tid & 7;                       // (256+tid)&7 == tid&7
  const int jj0 = tid >> 3, jj1 = (256 + tid) >> 3;
  const int r0 = jj0 / 14, wq0 = jj0 - r0 * 14;
  const int r1 = jj1 / 14, wq1 = jj1 - r1 * 14;
  const bool s1v = tid < 192;
  const int h0 = oh0 + r0 - 1, h1 = oh0 + r1 - 1;
  const bool h0v = (unsigned)h0 < 56u;
  const bool h1v = s1v && ((unsigned)h1 < 56u);
  unsigned short* dst0 = &xs[(r0 * 58 + 1 + wq0 * 4) * CS + c8 * 8];
  unsigned short* dst1 = &xs[(r1 * 58 + 1 + wq1 * 4) * CS + c8 * 8];

  const float* xt0 = x + (size_t)(b2 * 2) * 64 * 3136;
  const float* xt1 = xt0 + (size_t)64 * 3136;

  // ---- stage tile0: fp32 -> RNE bf16 -> xs (transposed), borders zeroed ----
  {
    v8s z;
#pragma unroll
    for (int e = 0; e < 8; ++e) z[e] = 0;
    if (h0v) {
      const float* xb = xt0 + (size_t)(c8 * 8) * 3136 + h0 * 56 + wq0 * 4;
      v4f f[8];
#pragma unroll
      for (int jc = 0; jc < 8; ++jc) f[jc] = *(const v4f*)&xb[(size_t)jc * 3136];
#pragma unroll
      for (int k = 0; k < 4; ++k) {
        v8s pk;
#pragma unroll
        for (int jc = 0; jc < 8; ++jc) pk[jc] = (short)rne_bf16(f[jc][k]);
        *(v8s*)&dst0[k * CS] = pk;
      }
    } else {
#pragma unroll
      for (int k = 0; k < 4; ++k) *(v8s*)&dst0[k * CS] = z;
    }
    if (s1v) {
      if (h1v) {
        const float* xb = xt0 + (size_t)(c8 * 8) * 3136 + h1 * 56 + wq1 * 4;
        v4f f[8];
#pragma unroll
        for (int jc = 0; jc < 8; ++jc) f[jc] = *(const v4f*)&xb[(size_t)jc * 3136];
#pragma unroll
        for (int k = 0; k < 4; ++k) {
          v8s pk;
#pragma unroll
          for (int jc = 0; jc < 8; ++jc) pk[jc] = (short)rne_bf16(f[jc][k]);
          *(v8s*)&dst1[k * CS] = pk;
        }
      } else {
#pragma unroll
        for (int k = 0; k < 4; ++k) *(v8s*)&dst1[k * CS] = z;
      }
    }
    // col borders (w = -1 and 56): 4 rows * 2 cols * 8 octets = 64 slots
    if (tid < 64) {
      int r = tid >> 4, q = tid & 15;
      int col = (q >> 3) ? 57 : 0;
      *(v8s*)&xs[(r * 58 + col) * CS + (q & 7) * 8] = z;
    }
  }

  // ---- W fragments; half-pos double buffer (issued before barrier) ----
  const unsigned short* wt0 = Wt2 + lane * 8;
  v8s wa[4], wb[4];
#define WLOADH(POS, HALF, BUF)                                                 \
  {                                                                            \
    _Pragma("unroll") for (int kk2 = 0; kk2 < 2; ++kk2) {                      \
      _Pragma("unroll") for (int gi = 0; gi < 2; ++gi) {                       \
        BUF[kk2 * 2 + gi] = *(const v8s*)(                                     \
            wt0 + ((((POS)*4 + (HALF)*2 + kk2) * 4 + gg2 + gi) << 9));         \
      }                                                                        \
    }                                                                          \
  }
  WLOADH(0, 0, wa);
  WLOADH(0, 1, wb);
  __syncthreads();

  // ---- issue tile1 x prefetch NOW; results consumed after epilogue(t0) ----
  v4f pf[16];
  if (h0v) {
    const float* xb = xt1 + (size_t)(c8 * 8) * 3136 + h0 * 56 + wq0 * 4;
#pragma unroll
    for (int jc = 0; jc < 8; ++jc) pf[jc] = *(const v4f*)&xb[(size_t)jc * 3136];
  }
  if (h1v) {
    const float* xb = xt1 + (size_t)(c8 * 8) * 3136 + h1 * 56 + wq1 * 4;
#pragma unroll
    for (int jc = 0; jc < 8; ++jc) pf[8 + jc] = *(const v4f*)&xb[(size_t)jc * 3136];
  }

  v16f acc[2][2];  // [n-group][sp tile]
#define ACC_ZERO                                                               \
  _Pragma("unroll") for (int a = 0; a < 2; ++a)                                \
  _Pragma("unroll") for (int s = 0; s < 2; ++s)                                \
  _Pragma("unroll") for (int e = 0; e < 16; ++e) acc[a][s][e] = 0.0f;

#define COMPH(POS, HALF, BUF)                                                  \
  {                                                                            \
    const int kh = (POS) / 3, kw = (POS) % 3;                                  \
    const unsigned short* p0 = xs + ((rw + kh) * 58 + kw + lj) * CS + lh * 8;  \
    const unsigned short* p1 = xs + ((rw + kh) * 58 + kw + lj1) * CS + lh * 8; \
    _Pragma("unroll") for (int kk2 = 0; kk2 < 2; ++kk2) {                      \
      v8s f0 = *(const v8s*)(p0 + ((HALF)*2 + kk2) * 16);                      \
      v8s f1 = *(const v8s*)(p1 + ((HALF)*2 + kk2) * 16);                      \
      _Pragma("unroll") for (int gi = 0; gi < 2; ++gi) {                       \
        acc[gi][0] = __builtin_amdgcn_mfma_f32_32x32x16_bf16(BUF[kk2 * 2 + gi], f0, acc[gi][0], 0, 0, 0); \
        acc[gi][1] = __builtin_amdgcn_mfma_f32_32x32x16_bf16(BUF[kk2 * 2 + gi], f1, acc[gi][1], 0, 0, 0); \
      }                                                                        \
    }                                                                          \
  }

#define LADDER                                                                 \
  COMPH(0, 0, wa); WLOADH(1, 0, wa); COMPH(0, 1, wb); WLOADH(1, 1, wb);        \
  COMPH(1, 0, wa); WLOADH(2, 0, wa); COMPH(1, 1, wb); WLOADH(2, 1, wb);        \
  COMPH(2, 0, wa); WLOADH(3, 0, wa); COMPH(2, 1, wb); WLOADH(3, 1, wb);        \
  COMPH(3, 0, wa); WLOADH(4, 0, wa); COMPH(3, 1, wb); WLOADH(4, 1, wb);        \
  COMPH(4, 0, wa); WLOADH(5, 0, wa); COMPH(4, 1, wb); WLOADH(5, 1, wb);        \
  COMPH(5, 0, wa); WLOADH(6, 0, wa); COMPH(5, 1, wb); WLOADH(6, 1, wb);        \
  COMPH(6, 0, wa); WLOADH(7, 0, wa); COMPH(6, 1, wb); WLOADH(7, 1, wb);        \
  COMPH(7, 0, wa); WLOADH(8, 0, wa); COMPH(7, 1, wb); WLOADH(8, 1, wb);        \
  COMPH(8, 0, wa); COMPH(8, 1, wb);

  // epilogue: 2 row-passes, fbuf[128][60] transpose (aliases xs) -> v4f stores
#define EPI(BB)                                                                \
  __syncthreads(); /* all xs reads done; fbuf may alias xs */                  \
  _Pragma("unroll") for (int p = 0; p < 2; ++p) {                              \
    if ((wv & 1) == p && lj < 28) {                                            \
      _Pragma("unroll") for (int gi = 0; gi < 2; ++gi) {                       \
        _Pragma("unroll") for (int e = 0; e < 16; ++e) {                       \
          int chl = (e & 3) + 8 * (e >> 2) + 4 * lh; /* C/D layout, verified */\
          int ch = (gg2 + gi) * 32 + chl;                                      \
          fbuf[ch * 60 + lj] = acc[gi][0][e];                                  \
          fbuf[ch * 60 + 28 + lj] = acc[gi][1][e];                             \
        }                                                                      \
      }                                                                        \
    }                                                                          \
    __syncthreads();                                                           \
    {                                                                          \
      int ch = tid >> 1, hf = tid & 1;                                         \
      float bb = qb[ch];                                                       \
      const float* src = &fbuf[ch * 60 + hf * 28];                             \
      float* dst = out + (size_t)((BB)*128 + ch) * 3136 + (oh0 + p) * 56 + hf * 28; \
      _Pragma("unroll") for (int k = 0; k < 7; ++k) {                          \
        v4f v = *(const v4f*)&src[k * 4];                                      \
        v[0] += bb; v[1] += bb; v[2] += bb; v[3] += bb;                        \
        *(v4f*)&dst[k * 4] = v;                                                \
      }                                                                        \
    }                                                                          \
    if (p == 0) __syncthreads();                                               \
  }

  // ================= tile 0 =================
  ACC_ZERO;
  LADDER;            // t1 prefetch loads in flight underneath
  EPI(b2 * 2);
  __syncthreads();   // all fbuf readers done before t1 overwrites xs

  // ---- stage tile1 from pf regs (loads completed during t0 compute) ----
  {
    v8s z;
#pragma unroll
    for (int e = 0; e < 8; ++e) z[e] = 0;
    if (h0v) {
#pragma unroll
      for (int k = 0; k < 4; ++k) {
        v8s pk;
#pragma unroll
        for (int jc = 0; jc < 8; ++jc) pk[jc] = (short)rne_bf16(pf[jc][k]);
        *(v8s*)&dst0[k * CS] = pk;
      }
    } else {
#pragma unroll
      for (int k = 0; k < 4; ++k) *(v8s*)&dst0[k * CS] = z;
    }
    if (s1v) {
      if (h1v) {
#pragma unroll
        for (int k = 0; k < 4; ++k) {
          v8s pk;
#pragma unroll
          for (int jc = 0; jc < 8; ++jc) pk[jc] = (short)rne_bf16(pf[8 + jc][k]);
          *(v8s*)&dst1[k * CS] = pk;
        }
      } else {
#pragma unroll
        for (int k = 0; k < 4; ++k) *(v8s*)&dst1[k * CS] = z;
      }
    }
    if (tid < 64) {
      int r = tid >> 4, q = tid & 15;
      int col = (q >> 3) ? 57 : 0;
      *(v8s*)&xs[(r * 58 + col) * CS + (q & 7) * 8] = z;
    }
  }
  WLOADH(0, 0, wa);  // W for t1 pos0 (L2-hot)
  WLOADH(0, 1, wb);
  __syncthreads();

  // ================= tile 1 =================
  ACC_ZERO;
  LADDER;
  EPI(b2 * 2 + 1);
}

extern "C" void kernel_launch(void* const* d_in, const int* in_sizes, int n_in,
                              void* d_out, int out_size, void* d_ws, size_t ws_size,
                              hipStream_t stream) {
  const float* x = (const float*)d_in[0];     // [32,64,56,56]
  const float* w = (const float*)d_in[1];     // [128,64,3,3]
  const float* bias = (const float*)d_in[2];  // [128]
  float* out = (float*)d_out;                 // [32,128,56,56] fp32

  unsigned short* Wt2 = (unsigned short*)d_ws;  // 147 KB

  wprep<<<32, 256, 0, stream>>>(w, Wt2);
  conv<<<dim3(28, 16), 256, 0, stream>>>(x, Wt2, bias, out);
}

// Round 6
// 110.925 us; speedup vs baseline: 1.1379x; 1.0319x over previous
//
#include <hip/hip_runtime.h>

typedef short v8s __attribute__((ext_vector_type(8)));
typedef float v4f __attribute__((ext_vector_type(4)));
typedef float v16f __attribute__((ext_vector_type(16)));

// RNE float -> bf16 (matches float_quantize(exp=8, man=7) for these inputs).
__device__ __forceinline__ unsigned short rne_bf16(float f) {
  unsigned u = __float_as_uint(f);
  return (unsigned short)((u + 0x7fffu + ((u >> 16) & 1u)) >> 16);
}
__device__ __forceinline__ float qbf(float f) {
  return __uint_as_float(((unsigned)rne_bf16(f)) << 16);
}

#define CS 72               // LDS col stride (shorts): 144 B
#define XSZ (4 * 58 * CS)   // shorts per x buffer (16704)

// ---------------------------------------------------------------------------
// wprep: 32 blocks. weights -> fragment-major Wt2:
//   Wt2[((pos*4 + kk)*4 + g)*512 + lane*8 + (c&7)],  g = n>>5 (0..3)
//   lane = (n&31) + 32*((c>>3)&1), kk = c>>4
// ---------------------------------------------------------------------------
__global__ __launch_bounds__(256) void wprep(const float* __restrict__ w,
                                             unsigned short* __restrict__ Wt2) {
  int t = blockIdx.x * 256 + threadIdx.x;  // 0..8191 = n*64 + c
  int n = t >> 6, c = t & 63;
  int kk = c >> 4;
  int lane = (n & 31) + 32 * ((c >> 3) & 1);
  const float* src = w + (size_t)t * 9;
#pragma unroll
  for (int pos = 0; pos < 9; ++pos) {
    int idx = (((pos * 4 + kk) * 4 + (n >> 5)) << 9) + lane * 8 + (c & 7);
    Wt2[idx] = rne_bf16(src[pos]);
  }
}

// ---------------------------------------------------------------------------
// conv, round 6: barrier-minimal, store-direct, latency-covering.
// R2-R5 post-mortem: 4 structures all ~43us = hbm_bytes/1.9TB/s; every pipe
// idle -> memory-LATENCY bound (Little's law: need ~5.7MB in flight, had
// ~1.7MB). Causes: ~6 barriers/tile each forcing vmcnt(0) drain (loads AND
// stores), and HBM-silent compute phases in lockstep across blocks.
// This version: grid (28,16), 2 tiles (batches) per block.
//  - ALL x loads for BOTH tiles issued at kernel start (64KB/block in flight
//    x 448 resident blocks = ~28MB -> BW-saturating burst).
//  - xs double-buffered (2x33KB): exactly TWO __syncthreads per block.
//  - epilogue: direct predicated dword stores from acc (no LDS transpose,
//    no barriers; 64 independent fire-and-forget stores/wave).
// Accumulation order per output chain identical to the verified kernel.
// ---------------------------------------------------------------------------
__global__ __launch_bounds__(256, 2) void conv(const float* __restrict__ x,
                                               const unsigned short* __restrict__ Wt2,
                                               const float* __restrict__ bias,
                                               float* __restrict__ out) {
  __shared__ __align__(16) char smem[2 * XSZ * 2 + 512];
  unsigned short* xs0 = (unsigned short*)smem;   // [4 rows][58 cols][64 c]
  unsigned short* xs1 = xs0 + XSZ;
  float* qb = (float*)(smem + 2 * XSZ * 2);      // 128 quantized biases

  const int pair = blockIdx.x, b2 = blockIdx.y;
  const int oh0 = pair * 2;
  const int tid = threadIdx.x;
  const int wv = tid >> 6, lane = tid & 63;
  const int lj = lane & 31, lh = lane >> 5;
  const int lj1 = 28 + (lj < 27 ? lj : 27);  // sp-tile1 col offset (clamped)
  const int rw = wv & 1;                     // wave's output row within pair
  const int gg2 = (wv >> 1) * 2;             // wave's first 32-ch group

  if (tid < 128) qb[tid] = qbf(bias[tid]);

  // slot decode (448 slots = 4r * 8c8 * 14wq): slot0 = tid, slot1 = 256+tid.
  const int c8 = tid & 7;
  const int jj0 = tid >> 3, jj1 = 32 + (tid >> 3);
  const int r0 = jj0 / 14, wq0 = jj0 - r0 * 14;
  const int r1 = jj1 / 14, wq1 = jj1 - r1 * 14;
  const bool s1v = tid < 192;
  const int h0 = oh0 + r0 - 1, h1 = oh0 + r1 - 1;
  const bool h0v = (unsigned)h0 < 56u;
  const bool h1v = s1v && ((unsigned)h1 < 56u);
  const int off0 = (r0 * 58 + 1 + wq0 * 4) * CS + c8 * 8;
  const int off1 = (r1 * 58 + 1 + wq1 * 4) * CS + c8 * 8;

  const float* xt0 = x + (size_t)(b2 * 2) * 64 * 3136;
  const float* xt1 = xt0 + (size_t)64 * 3136;

  // ---- issue ALL x loads for BOTH tiles up front (32 v4f in flight) ----
  v4f f0[8], f1[8], p0f[8], p1f[8];
  if (h0v) {
    const float* a = xt0 + (size_t)(c8 * 8) * 3136 + h0 * 56 + wq0 * 4;
#pragma unroll
    for (int jc = 0; jc < 8; ++jc) f0[jc] = *(const v4f*)&a[(size_t)jc * 3136];
  }
  if (h1v) {
    const float* a = xt0 + (size_t)(c8 * 8) * 3136 + h1 * 56 + wq1 * 4;
#pragma unroll
    for (int jc = 0; jc < 8; ++jc) f1[jc] = *(const v4f*)&a[(size_t)jc * 3136];
  }
  if (h0v) {
    const float* a = xt1 + (size_t)(c8 * 8) * 3136 + h0 * 56 + wq0 * 4;
#pragma unroll
    for (int jc = 0; jc < 8; ++jc) p0f[jc] = *(const v4f*)&a[(size_t)jc * 3136];
  }
  if (h1v) {
    const float* a = xt1 + (size_t)(c8 * 8) * 3136 + h1 * 56 + wq1 * 4;
#pragma unroll
    for (int jc = 0; jc < 8; ++jc) p1f[jc] = *(const v4f*)&a[(size_t)jc * 3136];
  }

  v8s z;
#pragma unroll
  for (int e = 0; e < 8; ++e) z[e] = 0;

#define QWRITE(XS, OFF, F)                                                     \
  {                                                                            \
    _Pragma("unroll") for (int k = 0; k < 4; ++k) {                            \
      v8s pk;                                                                  \
      _Pragma("unroll") for (int jc = 0; jc < 8; ++jc)                         \
          pk[jc] = (short)rne_bf16(F[jc][k]);                                  \
      *(v8s*)&(XS)[(OFF) + k * CS] = pk;                                       \
    }                                                                          \
  }
#define ZWRITE(XS, OFF)                                                        \
  { _Pragma("unroll") for (int k = 0; k < 4; ++k) *(v8s*)&(XS)[(OFF) + k * CS] = z; }

  // ---- stage tile0 into xs0 ----
  if (h0v) QWRITE(xs0, off0, f0) else ZWRITE(xs0, off0);
  if (s1v) { if (h1v) QWRITE(xs0, off1, f1) else ZWRITE(xs0, off1); }
  // zero col borders of BOTH buffers (w = -1 and 56)
  if (tid < 128) {
    int t = tid & 63, r = t >> 4, q = t & 15;
    int col = (q >> 3) ? 57 : 0;
    unsigned short* B = (tid < 64) ? xs0 : xs1;
    *(v8s*)&B[(r * 58 + col) * CS + (q & 7) * 8] = z;
  }

  // ---- W fragments; half-pos double buffer ----
  const unsigned short* wt0 = Wt2 + lane * 8;
  v8s wa[4], wb[4];
#define WLOADH(POS, HALF, BUF)                                                 \
  {                                                                            \
    _Pragma("unroll") for (int kk2 = 0; kk2 < 2; ++kk2) {                      \
      _Pragma("unroll") for (int gi = 0; gi < 2; ++gi) {                       \
        BUF[kk2 * 2 + gi] = *(const v8s*)(                                     \
            wt0 + ((((POS)*4 + (HALF)*2 + kk2) * 4 + gg2 + gi) << 9));         \
      }                                                                        \
    }                                                                          \
  }
  WLOADH(0, 0, wa);
  WLOADH(0, 1, wb);
  __syncthreads();  // barrier #1: xs0 visible (vmcnt drain covers pf too)

  v16f acc[2][2];  // [n-group][sp tile]
#define ACC_ZERO                                                               \
  _Pragma("unroll") for (int a = 0; a < 2; ++a)                                \
  _Pragma("unroll") for (int s = 0; s < 2; ++s)                                \
  _Pragma("unroll") for (int e = 0; e < 16; ++e) acc[a][s][e] = 0.0f;

#define COMPH(XS, POS, HALF, BUF)                                              \
  {                                                                            \
    const int kh = (POS) / 3, kw = (POS) % 3;                                  \
    const unsigned short* p0 = (XS) + ((rw + kh) * 58 + kw + lj) * CS + lh * 8;  \
    const unsigned short* p1 = (XS) + ((rw + kh) * 58 + kw + lj1) * CS + lh * 8; \
    _Pragma("unroll") for (int kk2 = 0; kk2 < 2; ++kk2) {                      \
      v8s q0 = *(const v8s*)(p0 + ((HALF)*2 + kk2) * 16);                      \
      v8s q1 = *(const v8s*)(p1 + ((HALF)*2 + kk2) * 16);                      \
      _Pragma("unroll") for (int gi = 0; gi < 2; ++gi) {                       \
        acc[gi][0] = __builtin_amdgcn_mfma_f32_32x32x16_bf16(BUF[kk2 * 2 + gi], q0, acc[gi][0], 0, 0, 0); \
        acc[gi][1] = __builtin_amdgcn_mfma_f32_32x32x16_bf16(BUF[kk2 * 2 + gi], q1, acc[gi][1], 0, 0, 0); \
      }                                                                        \
    }                                                                          \
  }

#define LADDER(XS)                                                             \
  COMPH(XS, 0, 0, wa); WLOADH(1, 0, wa); COMPH(XS, 0, 1, wb); WLOADH(1, 1, wb); \
  COMPH(XS, 1, 0, wa); WLOADH(2, 0, wa); COMPH(XS, 1, 1, wb); WLOADH(2, 1, wb); \
  COMPH(XS, 2, 0, wa); WLOADH(3, 0, wa); COMPH(XS, 2, 1, wb); WLOADH(3, 1, wb); \
  COMPH(XS, 3, 0, wa); WLOADH(4, 0, wa); COMPH(XS, 3, 1, wb); WLOADH(4, 1, wb); \
  COMPH(XS, 4, 0, wa); WLOADH(5, 0, wa); COMPH(XS, 4, 1, wb); WLOADH(5, 1, wb); \
  COMPH(XS, 5, 0, wa); WLOADH(6, 0, wa); COMPH(XS, 5, 1, wb); WLOADH(6, 1, wb); \
  COMPH(XS, 6, 0, wa); WLOADH(7, 0, wa); COMPH(XS, 6, 1, wb); WLOADH(7, 1, wb); \
  COMPH(XS, 7, 0, wa); WLOADH(8, 0, wa); COMPH(XS, 7, 1, wb); WLOADH(8, 1, wb); \
  COMPH(XS, 8, 0, wa); COMPH(XS, 8, 1, wb);

  // direct store from acc: per (gi,e), 28-lane dword runs for both sp tiles.
  // ch = gg2*32 + gi*32 + (e&3)+8*(e>>2) + 4*lh  (C/D layout, verified)
#define STORES(BB)                                                             \
  if (lj < 28) {                                                               \
    float* ob = out + ((size_t)((BB)*128 + gg2 * 32 + 4 * lh)) * 3136 +        \
                (size_t)(oh0 + rw) * 56 + lj;                                  \
    _Pragma("unroll") for (int gi = 0; gi < 2; ++gi) {                         \
      _Pragma("unroll") for (int e = 0; e < 16; ++e) {                         \
        const int chp = (e & 3) + 8 * (e >> 2);                                \
        float bb = qb[gg2 * 32 + gi * 32 + chp + 4 * lh];                      \
        float* d = ob + (size_t)(gi * 32 + chp) * 3136;                        \
        d[0] = acc[gi][0][e] + bb;                                             \
        d[28] = acc[gi][1][e] + bb;                                            \
      }                                                                        \
    }                                                                          \
  }

  // ================= tile 0 =================
  ACC_ZERO;
  LADDER(xs0);
  WLOADH(0, 0, wa);  // t1 pos0 W issued before stores (avoids store-drain wait)
  WLOADH(0, 1, wb);
  STORES(b2 * 2);

  // ---- stage tile1 into xs1 (pf loads long since landed) ----
  if (h0v) QWRITE(xs1, off0, p0f) else ZWRITE(xs1, off0);
  if (s1v) { if (h1v) QWRITE(xs1, off1, p1f) else ZWRITE(xs1, off1); }
  __syncthreads();  // barrier #2: xs1 visible (other waves done with xs0)

  // ================= tile 1 =================
  ACC_ZERO;
  LADDER(xs1);
  STORES(b2 * 2 + 1);
}

extern "C" void kernel_launch(void* const* d_in, const int* in_sizes, int n_in,
                              void* d_out, int out_size, void* d_ws, size_t ws_size,
                              hipStream_t stream) {
  const float* x = (const float*)d_in[0];     // [32,64,56,56]
  const float* w = (const float*)d_in[1];     // [128,64,3,3]
  const float* bias = (const float*)d_in[2];  // [128]
  float* out = (float*)d_out;                 // [32,128,56,56] fp32

  unsigned short* Wt2 = (unsigned short*)d_ws;  // 147 KB

  wprep<<<32, 256, 0, stream>>>(w, Wt2);
  conv<<<dim3(28, 16), 256, 0, stream>>>(x, Wt2, bias, out);
}

// Round 7
// 105.909 us; speedup vs baseline: 1.1918x; 1.0474x over previous
//
#include <hip/hip_runtime.h>

typedef short v8s __attribute__((ext_vector_type(8)));
typedef float v4f __attribute__((ext_vector_type(4)));
typedef float v16f __attribute__((ext_vector_type(16)));

// RNE float -> bf16 (matches float_quantize(exp=8, man=7) for these inputs).
__device__ __forceinline__ unsigned short rne_bf16(float f) {
  unsigned u = __float_as_uint(f);
  return (unsigned short)((u + 0x7fffu + ((u >> 16) & 1u)) >> 16);
}
__device__ __forceinline__ float qbf(float f) {
  return __uint_as_float(((unsigned)rne_bf16(f)) << 16);
}

#define CS 72  // LDS col stride (shorts): 144 B; bank-optimal for b128 reads

// ---------------------------------------------------------------------------
// wprep: 32 blocks. weights -> fragment-major Wt2:
//   Wt2[((pos*4 + kk)*4 + g)*512 + lane*8 + (c&7)],  g = n>>5 (0..3)
//   lane = (n&31) + 32*((c>>3)&1), kk = c>>4
// ---------------------------------------------------------------------------
__global__ __launch_bounds__(256) void wprep(const float* __restrict__ w,
                                             unsigned short* __restrict__ Wt2) {
  int t = blockIdx.x * 256 + threadIdx.x;  // 0..8191 = n*64 + c
  int n = t >> 6, c = t & 63;
  int kk = c >> 4;
  int lane = (n & 31) + 32 * ((c >> 3) & 1);
  const float* src = w + (size_t)t * 9;
#pragma unroll
  for (int pos = 0; pos < 9; ++pos) {
    int idx = (((pos * 4 + kk) * 4 + (n >> 5)) << 9) + lane * 8 + (c & 7);
    Wt2[idx] = rne_bf16(src[pos]);
  }
}

// ---------------------------------------------------------------------------
// conv, round 7: minimal serial chain, ONE barrier, max co-resident blocks.
// R6 post-mortem: compiler emits s_waitcnt vmcnt(0) before EVERY s_barrier,
// so R6's "t1 prefetch hides under t0 compute" was drained at barrier #1 —
// the structure degenerated to fully-serial (load->wait-all->compute->store),
// matching the ~38-44us plateau of R3-R6. This version shortens the chain
// instead: 896 single-tile blocks (2 rows x 128 ch), single 33KB xs,
// __launch_bounds__(256,3) -> 3 blocks/CU, 12 waves/CU. Per block:
//   issue 16 loads -> quant+ds_write -> ONE barrier (drains only own loads,
//   needed anyway) -> ladder -> fire-and-forget stores -> exit.
// No post-ladder barrier: block i's stores overlap block j's ladder on the
// same CU; staggered HBM returns de-convoy the blocks.
// XCD swizzle (896%8==0, bijective): each XCD gets 4 whole batches x 28
// pairs -> neighbor-pair row-overlap re-reads are same-XCD L2 hits.
// Accumulation order per output chain identical to the verified kernel.
// ---------------------------------------------------------------------------
__global__ __launch_bounds__(256, 3) void conv(const float* __restrict__ x,
                                               const unsigned short* __restrict__ Wt2,
                                               const float* __restrict__ bias,
                                               float* __restrict__ out) {
  __shared__ __align__(16) char smem[4 * 58 * CS * 2 + 512];
  unsigned short* xs = (unsigned short*)smem;    // [4 rows][58 cols][64 c]
  float* qb = (float*)(smem + 4 * 58 * CS * 2);  // 128 quantized biases

  // bijective XCD swizzle: id -> (xcd = id&7, idx = id>>3), orig = xcd*112+idx
  const int id = blockIdx.x;
  const int orig = (id & 7) * 112 + (id >> 3);
  const int pair = orig % 28, b = orig / 28;
  const int oh0 = pair * 2;
  const int tid = threadIdx.x;
  const int wv = tid >> 6, lane = tid & 63;
  const int lj = lane & 31, lh = lane >> 5;
  const int lj1 = 28 + (lj < 27 ? lj : 27);  // sp-tile1 col offset (clamped)
  const int rw = wv & 1;                     // wave's output row within pair
  const int gg2 = (wv >> 1) * 2;             // wave's first 32-ch group

  // slot decode (448 slots = 4r * 8c8 * 14wq): slot0 = tid, slot1 = 256+tid.
  const int c8 = tid & 7;
  const int jj0 = tid >> 3, jj1 = 32 + (tid >> 3);
  const int r0 = jj0 / 14, wq0 = jj0 - r0 * 14;
  const int r1 = jj1 / 14, wq1 = jj1 - r1 * 14;
  const bool s1v = tid < 192;
  const int h0 = oh0 + r0 - 1, h1 = oh0 + r1 - 1;
  const bool h0v = (unsigned)h0 < 56u;
  const bool h1v = s1v && ((unsigned)h1 < 56u);
  const int off0 = (r0 * 58 + 1 + wq0 * 4) * CS + c8 * 8;
  const int off1 = (r1 * 58 + 1 + wq1 * 4) * CS + c8 * 8;

  const float* xt = x + (size_t)b * 64 * 3136;

  // ---- issue this tile's 16 loads immediately ----
  v4f f0[8], f1[8];
  if (h0v) {
    const float* a = xt + (size_t)(c8 * 8) * 3136 + h0 * 56 + wq0 * 4;
#pragma unroll
    for (int jc = 0; jc < 8; ++jc) f0[jc] = *(const v4f*)&a[(size_t)jc * 3136];
  }
  if (h1v) {
    const float* a = xt + (size_t)(c8 * 8) * 3136 + h1 * 56 + wq1 * 4;
#pragma unroll
    for (int jc = 0; jc < 8; ++jc) f1[jc] = *(const v4f*)&a[(size_t)jc * 3136];
  }

  // ---- W fragments pos0 (L2-hot after first blocks) + bias while waiting ----
  const unsigned short* wt0 = Wt2 + lane * 8;
  v8s wa[4], wb[4];
#define WLOADH(POS, HALF, BUF)                                                 \
  {                                                                            \
    _Pragma("unroll") for (int kk2 = 0; kk2 < 2; ++kk2) {                      \
      _Pragma("unroll") for (int gi = 0; gi < 2; ++gi) {                       \
        BUF[kk2 * 2 + gi] = *(const v8s*)(                                     \
            wt0 + ((((POS)*4 + (HALF)*2 + kk2) * 4 + gg2 + gi) << 9));         \
      }                                                                        \
    }                                                                          \
  }
  WLOADH(0, 0, wa);
  WLOADH(0, 1, wb);
  if (tid < 128) qb[tid] = qbf(bias[tid]);

  v8s z;
#pragma unroll
  for (int e = 0; e < 8; ++e) z[e] = 0;

  // zero col borders (w = -1 and 56): independent of loads
  if (tid < 64) {
    int r = tid >> 4, q = tid & 15;
    int col = (q >> 3) ? 57 : 0;
    *(v8s*)&xs[(r * 58 + col) * CS + (q & 7) * 8] = z;
  }

#define QWRITE(OFF, F)                                                         \
  {                                                                            \
    _Pragma("unroll") for (int k = 0; k < 4; ++k) {                            \
      v8s pk;                                                                  \
      _Pragma("unroll") for (int jc = 0; jc < 8; ++jc)                         \
          pk[jc] = (short)rne_bf16(F[jc][k]);                                  \
      *(v8s*)&xs[(OFF) + k * CS] = pk;                                         \
    }                                                                          \
  }
#define ZWRITE(OFF)                                                            \
  { _Pragma("unroll") for (int k = 0; k < 4; ++k) *(v8s*)&xs[(OFF) + k * CS] = z; }

  // ---- quant + ds_write (first use of f0/f1 -> fine-grained vmcnt wait) ----
  if (h0v) QWRITE(off0, f0) else ZWRITE(off0);
  if (s1v) { if (h1v) QWRITE(off1, f1) else ZWRITE(off1); }

  __syncthreads();  // the ONLY barrier: xs visible; drains only own loads

  v16f acc[2][2];  // [n-group][sp tile]
#pragma unroll
  for (int a = 0; a < 2; ++a)
#pragma unroll
    for (int s = 0; s < 2; ++s)
#pragma unroll
      for (int e = 0; e < 16; ++e) acc[a][s][e] = 0.0f;

#define COMPH(POS, HALF, BUF)                                                  \
  {                                                                            \
    const int kh = (POS) / 3, kw = (POS) % 3;                                  \
    const unsigned short* p0 = xs + ((rw + kh) * 58 + kw + lj) * CS + lh * 8;  \
    const unsigned short* p1 = xs + ((rw + kh) * 58 + kw + lj1) * CS + lh * 8; \
    _Pragma("unroll") for (int kk2 = 0; kk2 < 2; ++kk2) {                      \
      v8s q0 = *(const v8s*)(p0 + ((HALF)*2 + kk2) * 16);                      \
      v8s q1 = *(const v8s*)(p1 + ((HALF)*2 + kk2) * 16);                      \
      _Pragma("unroll") for (int gi = 0; gi < 2; ++gi) {                       \
        acc[gi][0] = __builtin_amdgcn_mfma_f32_32x32x16_bf16(BUF[kk2 * 2 + gi], q0, acc[gi][0], 0, 0, 0); \
        acc[gi][1] = __builtin_amdgcn_mfma_f32_32x32x16_bf16(BUF[kk2 * 2 + gi], q1, acc[gi][1], 0, 0, 0); \
      }                                                                        \
    }                                                                          \
  }

  COMPH(0, 0, wa); WLOADH(1, 0, wa); COMPH(0, 1, wb); WLOADH(1, 1, wb);
  COMPH(1, 0, wa); WLOADH(2, 0, wa); COMPH(1, 1, wb); WLOADH(2, 1, wb);
  COMPH(2, 0, wa); WLOADH(3, 0, wa); COMPH(2, 1, wb); WLOADH(3, 1, wb);
  COMPH(3, 0, wa); WLOADH(4, 0, wa); COMPH(3, 1, wb); WLOADH(4, 1, wb);
  COMPH(4, 0, wa); WLOADH(5, 0, wa); COMPH(4, 1, wb); WLOADH(5, 1, wb);
  COMPH(5, 0, wa); WLOADH(6, 0, wa); COMPH(5, 1, wb); WLOADH(6, 1, wb);
  COMPH(6, 0, wa); WLOADH(7, 0, wa); COMPH(6, 1, wb); WLOADH(7, 1, wb);
  COMPH(7, 0, wa); WLOADH(8, 0, wa); COMPH(7, 1, wb); WLOADH(8, 1, wb);
  COMPH(8, 0, wa); COMPH(8, 1, wb);

  // ---- direct fire-and-forget stores from acc (no barrier, no LDS) ----
  // ch = gg2*32 + gi*32 + (e&3)+8*(e>>2) + 4*lh  (C/D layout, verified)
  if (lj < 28) {
    float* ob = out + ((size_t)(b * 128 + gg2 * 32 + 4 * lh)) * 3136 +
                (size_t)(oh0 + rw) * 56 + lj;
#pragma unroll
    for (int gi = 0; gi < 2; ++gi) {
#pragma unroll
      for (int e = 0; e < 16; ++e) {
        const int chp = (e & 3) + 8 * (e >> 2);
        float bb = qb[gg2 * 32 + gi * 32 + chp + 4 * lh];
        float* d = ob + (size_t)(gi * 32 + chp) * 3136;
        d[0] = acc[gi][0][e] + bb;
        d[28] = acc[gi][1][e] + bb;
      }
    }
  }
}

extern "C" void kernel_launch(void* const* d_in, const int* in_sizes, int n_in,
                              void* d_out, int out_size, void* d_ws, size_t ws_size,
                              hipStream_t stream) {
  const float* x = (const float*)d_in[0];     // [32,64,56,56]
  const float* w = (const float*)d_in[1];     // [128,64,3,3]
  const float* bias = (const float*)d_in[2];  // [128]
  float* out = (float*)d_out;                 // [32,128,56,56] fp32

  unsigned short* Wt2 = (unsigned short*)d_ws;  // 147 KB

  wprep<<<32, 256, 0, stream>>>(w, Wt2);
  conv<<<896, 256, 0, stream>>>(x, Wt2, bias, out);
}